// Round 10
// baseline (377.476 us; speedup 1.0000x reference)
//
#include <hip/hip_runtime.h>
#include <hip/hip_bf16.h>
#include <cstdint>

typedef unsigned short U16;
typedef float f32x4 __attribute__((ext_vector_type(4)));
typedef __bf16 bf16x8 __attribute__((ext_vector_type(8)));

#define DEVINL __device__ __forceinline__

DEVINL U16 f2bf(float f) {
    unsigned u = __float_as_uint(f);
    return (U16)((u + 0x7FFFu + ((u >> 16) & 1u)) >> 16);  // RN-even
}
DEVINL float bf2f(U16 s) { return __uint_as_float(((unsigned)s) << 16); }

DEVINL void gld16(const void* g, void* l) {
    __builtin_amdgcn_global_load_lds(
        (const __attribute__((address_space(1))) void*)g,
        (__attribute__((address_space(3))) void*)l, 16, 0, 0);
}

#define MFMA_BF16 __builtin_amdgcn_mfma_f32_16x16x32_bf16

// ---------------- weight transpose + cast: wt[n][k] = (bf16) w[k][n] ----------------
__global__ __launch_bounds__(256) void tcast_kernel(const float* __restrict__ w,
                                                    U16* __restrict__ wt, int K, int N) {
    __shared__ float tile[32][33];
    int n0 = blockIdx.x * 32, k0 = blockIdx.y * 32;
    int tx = threadIdx.x, ty = threadIdx.y;  // 32 x 8
#pragma unroll
    for (int i = 0; i < 32; i += 8) tile[ty + i][tx] = w[(size_t)(k0 + ty + i) * N + (n0 + tx)];
    __syncthreads();
#pragma unroll
    for (int i = 0; i < 32; i += 8) wt[(size_t)(n0 + ty + i) * K + (k0 + tx)] = f2bf(tile[tx][ty + i]);
}

// ---------------- LayerNorm over 512, one wave per row, bf16 out ----------------
__global__ __launch_bounds__(256) void ln_kernel(const float* __restrict__ x,
                                                 const float* __restrict__ g,
                                                 const float* __restrict__ b,
                                                 U16* __restrict__ out) {
    int lane = threadIdx.x & 63;
    size_t row = (size_t)blockIdx.x * 4 + (threadIdx.x >> 6);
    const float4* xr = (const float4*)(x + row * 512);
    float4 v0 = xr[lane], v1 = xr[lane + 64];
    float s = (v0.x + v0.y) + (v0.z + v0.w) + (v1.x + v1.y) + (v1.z + v1.w);
    float sq = (v0.x * v0.x + v0.y * v0.y + v0.z * v0.z + v0.w * v0.w) +
               (v1.x * v1.x + v1.y * v1.y + v1.z * v1.z + v1.w * v1.w);
#pragma unroll
    for (int m = 1; m < 64; m <<= 1) { s += __shfl_xor(s, m); sq += __shfl_xor(sq, m); }
    float mu = s * (1.f / 512.f);
    float var = sq * (1.f / 512.f) - mu * mu;
    float rs = rsqrtf(var + 1e-5f);
    const float4* g4 = (const float4*)g;
    const float4* b4 = (const float4*)b;
    float4 gv = g4[lane], bv = b4[lane];
    ushort4 o;
    o.x = f2bf((v0.x - mu) * rs * gv.x + bv.x);
    o.y = f2bf((v0.y - mu) * rs * gv.y + bv.y);
    o.z = f2bf((v0.z - mu) * rs * gv.z + bv.z);
    o.w = f2bf((v0.w - mu) * rs * gv.w + bv.w);
    ((ushort4*)(out + row * 512))[lane] = o;
    gv = g4[lane + 64]; bv = b4[lane + 64];
    o.x = f2bf((v1.x - mu) * rs * gv.x + bv.x);
    o.y = f2bf((v1.y - mu) * rs * gv.y + bv.y);
    o.z = f2bf((v1.z - mu) * rs * gv.z + bv.z);
    o.w = f2bf((v1.w - mu) * rs * gv.w + bv.w);
    ((ushort4*)(out + row * 512))[lane + 64] = o;
}

// ---------------- 128x128 reg-dbuf ring-2 GEMM ----------------
// C[M,N] = A[M,K](bf16) * Bt[N,K](bf16)^T + bias (+gelu / +resid)
// 256 threads = 4 waves (2M x 2N), wave tile 64x64, BK=32, ring-2 x 16KB LDS.
// Per iter t: STAGE(t+2) [4 gld16 into buf t&1 -- safe: its reads drained at iter t-1's
// lgkmcnt(0)+barrier]; vmcnt(4) [t AND t+1 landed; t+2's 4 stay in flight -- counted,
// never 0 until tail]; barrier; issue 12 ds_read_b128 for tile t+1 into the OTHER frag
// set; sched_barrier(MFMA-only crosses); 16 MFMA on tile t's frags (loaded last iter);
// lgkmcnt(0); barrier.  => LDS reads execute UNDER the MFMA burst in every wave
// (within-wave read||MFMA overlap, the 2-phase stall fix), not by inter-wave luck.
// Swizzle (measured 0 conflicts R8/R9): phys 16B chunk = logical ^ ((row>>1)&3).
// K templated; executed as fully-static 16-iter chunks (frag-set parity & buffers fold).
// EPI 0: bf16 out (bias); EPI 1: fp32 out (bias+resid); EPI 2: bf16 out (bias+gelu-tanh)
template <int EPI, int K>
__global__ __launch_bounds__(256, 3) void gemm_rt(const U16* __restrict__ A,
                                                  const U16* __restrict__ Bt,
                                                  const float* __restrict__ bias,
                                                  const float* __restrict__ resid,
                                                  U16* __restrict__ outb,
                                                  float* __restrict__ outf,
                                                  int M, int N, int gridN) {
    // ring buffer b at b*8192 U16: A rows0-63 +0, A rows64-127 +2048, B r0-63 +4096, B r64-127 +6144
    __shared__ __align__(16) U16 smem[16384];

    const int tid = threadIdx.x;
    const int lane = tid & 63, wv = tid >> 6;
    const int lo = lane & 15, hi = lane >> 4;
    const int wm = wv >> 1, wn = wv & 1;  // 2 x 2 wave grid, wave tile 64x64

    const int nwg = gridDim.x, bid = blockIdx.x;
    const int swzb = (bid & 7) * (nwg >> 3) + (bid >> 3);
    const int bn = swzb % gridN, bm = swzb / gridN;

    // staging: row sr = tid>>2 (0..63; +64 for second line), phys chunk tid&3;
    // logical chunk = phys ^ ((row>>1)&3)
    const int sr = tid >> 2;
    const int lc = (tid & 3) ^ ((sr >> 1) & 3);
    const U16* gA0 = A + (size_t)(bm * 128 + sr) * K + lc * 8;
    const U16* gA1 = gA0 + (size_t)64 * K;
    const U16* gB0 = Bt + (size_t)(bn * 128 + sr) * K + lc * 8;
    const U16* gB1 = gB0 + (size_t)64 * K;

    // swizzled 16B-chunk offset for ds_read (U16 units): chunk = hi ^ ((lo>>1)&3)
    const int ck = (hi ^ ((lo >> 1) & 3)) << 3;
    const int aoff = (wm * 64 + lo) * 32 + ck;
    const int boff = 4096 + (wn * 64 + lo) * 32 + ck;

    f32x4 acc[4][4] = {};
    bf16x8 afA[4], bgA[4], afB[4], bgB[4];

#define RD(AF, BG, CB)                                                          \
    do {                                                                        \
        const U16* _Ab = smem + (CB) + aoff;                                    \
        const U16* _Bb = smem + (CB) + boff;                                    \
        _Pragma("unroll") for (int i = 0; i < 4; ++i)                           \
            AF[i] = *(const bf16x8*)(_Ab + i * 512);                            \
        _Pragma("unroll") for (int j = 0; j < 4; ++j)                           \
            BG[j] = *(const bf16x8*)(_Bb + j * 512);                            \
    } while (0)

#define MM(AF, BG)                                                              \
    do {                                                                        \
        __builtin_amdgcn_s_setprio(1);                                          \
        _Pragma("unroll") for (int i = 0; i < 4; ++i)                           \
            _Pragma("unroll") for (int j = 0; j < 4; ++j)                       \
                acc[i][j] = MFMA_BF16(AF[i], BG[j], acc[i][j], 0, 0, 0);        \
        __builtin_amdgcn_s_setprio(0);                                          \
    } while (0)

// one pipelined iteration; tt = position in 16-chunk (compile-time), TREL+2<LIM / +1<LIM
// gate tail staging/reads. Stage writes buf tt&1 (= (t+2)&1); reads target buf (tt+1)&1.
#define ITER(tt, TREL, LIM)                                                     \
    do {                                                                        \
        if ((TREL) + 2 < (LIM)) {                                               \
            U16* _l = smem + (((tt)&1) ? 8192 : 0) + tid * 8;                   \
            gld16(gAc0 + ((tt) + 2) * 32, _l);                                  \
            gld16(gAc1 + ((tt) + 2) * 32, _l + 2048);                           \
            gld16(gBc0 + ((tt) + 2) * 32, _l + 4096);                           \
            gld16(gBc1 + ((tt) + 2) * 32, _l + 6144);                           \
            asm volatile("s_waitcnt vmcnt(4)" ::: "memory");                    \
        } else {                                                                \
            asm volatile("s_waitcnt vmcnt(0)" ::: "memory");                    \
        }                                                                       \
        __builtin_amdgcn_s_barrier();                                           \
        if ((TREL) + 1 < (LIM)) {                                               \
            const int _cb = (((tt) + 1) & 1) ? 8192 : 0;                        \
            if (((tt)&1) == 0) RD(afB, bgB, _cb); else RD(afA, bgA, _cb);       \
        }                                                                       \
        __builtin_amdgcn_sched_barrier(0x8);                                    \
        if (((tt)&1) == 0) MM(afA, bgA); else MM(afB, bgB);                     \
        asm volatile("s_waitcnt lgkmcnt(0)" ::: "memory");                      \
        __builtin_amdgcn_s_barrier();                                           \
    } while (0)

    constexpr int NT = K >> 5;
    static_assert(NT >= 16 && (NT % 16) == 0, "K must be a multiple of 512");

    // prologue: stage tiles 0,1; wait tile0; read tile0 frags into set A
    {
        U16* _l = smem + tid * 8;
        gld16(gA0, _l);          gld16(gA1, _l + 2048);
        gld16(gB0, _l + 4096);   gld16(gB1, _l + 6144);
        U16* _l2 = smem + 8192 + tid * 8;
        gld16(gA0 + 32, _l2);        gld16(gA1 + 32, _l2 + 2048);
        gld16(gB0 + 32, _l2 + 4096); gld16(gB1 + 32, _l2 + 6144);
    }
    asm volatile("s_waitcnt vmcnt(4)" ::: "memory");
    __builtin_amdgcn_s_barrier();
    RD(afA, bgA, 0);

    // full 16-iter chunks (pipeline never tails here)
    for (int t0 = 0; t0 + 16 < NT; t0 += 16) {
        const U16* gAc0 = gA0 + (size_t)t0 * 32;
        const U16* gAc1 = gA1 + (size_t)t0 * 32;
        const U16* gBc0 = gB0 + (size_t)t0 * 32;
        const U16* gBc1 = gB1 + (size_t)t0 * 32;
#pragma unroll
        for (int tt = 0; tt < 16; ++tt) ITER(tt, tt, 1 << 30);
    }
    // tail chunk (last 16 tiles, static)
    {
        constexpr int t0 = NT - 16;
        const U16* gAc0 = gA0 + (size_t)t0 * 32;
        const U16* gAc1 = gA1 + (size_t)t0 * 32;
        const U16* gBc0 = gB0 + (size_t)t0 * 32;
        const U16* gBc1 = gB1 + (size_t)t0 * 32;
#pragma unroll
        for (int tt = 0; tt < 16; ++tt) ITER(tt, tt, 16);
    }

    // ---- epilogue: direct stores ----
    const int row0 = bm * 128 + wm * 64 + hi * 4;
    const int col0 = bn * 128 + wn * 64 + lo;
    float bc[4];
#pragma unroll
    for (int j = 0; j < 4; ++j) bc[j] = bias[col0 + j * 16];

    if (EPI == 1) {
#pragma unroll
        for (int i = 0; i < 4; ++i)
#pragma unroll
            for (int r = 0; r < 4; ++r) {
                const size_t rowb = (size_t)(row0 + i * 16 + r) * N;
#pragma unroll
                for (int j = 0; j < 4; ++j) {
                    const size_t idx = rowb + col0 + j * 16;
                    outf[idx] = acc[i][j][r] + bc[j] + resid[idx];
                }
            }
    } else {
#pragma unroll
        for (int i = 0; i < 4; ++i)
#pragma unroll
            for (int j = 0; j < 4; ++j)
#pragma unroll
                for (int r = 0; r < 4; ++r) {
                    float v = acc[i][j][r] + bc[j];
                    if (EPI == 2) {
                        // tanh-form GELU: v*sigmoid(2u), u = 0.79788456(v + 0.044715 v^3)
                        float u = v * (0.7978845608028654f + 0.0356774081f * v * v);
                        v = v / (1.f + __expf(-2.f * u));
                    }
                    outb[(size_t)(row0 + i * 16 + r) * N + col0 + j * 16] = f2bf(v);
                }
    }
#undef ITER
#undef MM
#undef RD
}

// ---------------- windowed attention: one block per (window, head) ----------------
// qkv: [32768][1536] bf16, layout [3][8][64] in last dim. o: [32768][512] bf16.
__global__ __launch_bounds__(256) void attn_kernel(const U16* __restrict__ qkv,
                                                   U16* __restrict__ o) {
    const int blk = blockIdx.x;
    const int w = blk >> 3, h = blk & 7;
    const int tid = threadIdx.x;
    const int lane = tid & 63, wv = tid >> 6;
    const int lo = lane & 15, hi = lane >> 4;

    __shared__ __align__(16) U16 Qs[64][72];
    __shared__ __align__(16) U16 Ks[64][72];
    __shared__ __align__(16) U16 Vt[64][72];  // V transposed: Vt[d][j]
    __shared__ __align__(16) U16 Ps[4][16][72];

    {
        const int r = tid >> 2;
        const int c0 = (tid & 3) << 4;
        const U16* p = qkv + (size_t)(w * 64 + r) * 1536 + h * 64 + c0;
        *(bf16x8*)&Ks[r][c0] = *(const bf16x8*)(p + 512);
        *(bf16x8*)&Ks[r][c0 + 8] = *(const bf16x8*)(p + 520);
        const U16* pv = p + 1024;
#pragma unroll
        for (int i = 0; i < 16; i++) Vt[c0 + i][r] = pv[i];
#pragma unroll
        for (int i = 0; i < 16; i++) Qs[r][c0 + i] = f2bf(bf2f(p[i]) * 0.125f);
    }
    __syncthreads();

    const int rb = wv * 16;  // this wave's 16 score rows
    f32x4 s[4] = {};
#pragma unroll
    for (int dc = 0; dc < 64; dc += 32) {
        bf16x8 a = *(const bf16x8*)&Qs[rb + lo][dc + hi * 8];
#pragma unroll
        for (int jb = 0; jb < 4; jb++) {
            bf16x8 bfr = *(const bf16x8*)&Ks[jb * 16 + lo][dc + hi * 8];
            s[jb] = MFMA_BF16(a, bfr, s[jb], 0, 0, 0);
        }
    }
#pragma unroll
    for (int r = 0; r < 4; r++) {
        float m = fmaxf(fmaxf(s[0][r], s[1][r]), fmaxf(s[2][r], s[3][r]));
#pragma unroll
        for (int msk = 1; msk < 16; msk <<= 1) m = fmaxf(m, __shfl_xor(m, msk));
        float e[4], sum = 0.f;
#pragma unroll
        for (int jb = 0; jb < 4; jb++) { e[jb] = expf(s[jb][r] - m); sum += e[jb]; }
#pragma unroll
        for (int msk = 1; msk < 16; msk <<= 1) sum += __shfl_xor(sum, msk);
        float inv = 1.f / sum;
#pragma unroll
        for (int jb = 0; jb < 4; jb++) Ps[wv][hi * 4 + r][jb * 16 + lo] = f2bf(e[jb] * inv);
    }
    __syncthreads();

    f32x4 oa[4] = {};
#pragma unroll
    for (int jc = 0; jc < 64; jc += 32) {
        bf16x8 a = *(const bf16x8*)&Ps[wv][lo][jc + hi * 8];
#pragma unroll
        for (int db = 0; db < 4; db++) {
            bf16x8 bfr = *(const bf16x8*)&Vt[db * 16 + lo][jc + hi * 8];
            oa[db] = MFMA_BF16(a, bfr, oa[db], 0, 0, 0);
        }
    }
#pragma unroll
    for (int db = 0; db < 4; db++)
#pragma unroll
        for (int r = 0; r < 4; r++)
            o[(size_t)(w * 64 + rb + hi * 4 + r) * 512 + h * 64 + db * 16 + lo] = f2bf(oa[db][r]);
}

// ---------------- launch ----------------
extern "C" void kernel_launch(void* const* d_in, const int* in_sizes, int n_in,
                              void* d_out, int out_size, void* d_ws, size_t ws_size,
                              hipStream_t stream) {
    const float* x = (const float*)d_in[0];
    const float* ln1_g = (const float*)d_in[1];
    const float* ln1_b = (const float*)d_in[2];
    const float* qkv_w = (const float*)d_in[3];
    const float* qkv_b = (const float*)d_in[4];
    const float* proj_w = (const float*)d_in[5];
    const float* proj_b = (const float*)d_in[6];
    const float* ln2_g = (const float*)d_in[7];
    const float* ln2_b = (const float*)d_in[8];
    const float* fc1_w = (const float*)d_in[9];
    const float* fc1_b = (const float*)d_in[10];
    const float* fc2_w = (const float*)d_in[11];
    const float* fc2_b = (const float*)d_in[12];
    float* out = (float*)d_out;

    char* ws = (char*)d_ws;
    U16* hbuf = (U16*)ws;                               // 32768*512 bf16
    U16* big = (U16*)(ws + 33554432);                   // 32768*2048 bf16 max
    U16* wt_qkv = (U16*)(ws + 33554432 + 134217728);    // 1536*512
    U16* wt_proj = wt_qkv + 1536 * 512;                 // 512*512
    U16* wt_fc1 = wt_proj + 512 * 512;                  // 2048*512
    U16* wt_fc2 = wt_fc1 + 2048 * 512;                  // 512*2048

    dim3 tb(32, 8);
    tcast_kernel<<<dim3(1536 / 32, 512 / 32), tb, 0, stream>>>(qkv_w, wt_qkv, 512, 1536);
    tcast_kernel<<<dim3(512 / 32, 512 / 32), tb, 0, stream>>>(proj_w, wt_proj, 512, 512);
    tcast_kernel<<<dim3(2048 / 32, 512 / 32), tb, 0, stream>>>(fc1_w, wt_fc1, 512, 2048);
    tcast_kernel<<<dim3(512 / 32, 2048 / 32), tb, 0, stream>>>(fc2_w, wt_fc2, 2048, 512);

    ln_kernel<<<8192, 256, 0, stream>>>(x, ln1_g, ln1_b, hbuf);
    gemm_rt<0, 512><<<3072, 256, 0, stream>>>(hbuf, wt_qkv, qkv_b, nullptr, big, nullptr, 32768, 1536, 12);
    attn_kernel<<<4096, 256, 0, stream>>>(big, hbuf);
    gemm_rt<1, 512><<<1024, 256, 0, stream>>>(hbuf, wt_proj, proj_b, x, nullptr, out, 32768, 512, 4);
    ln_kernel<<<8192, 256, 0, stream>>>(out, ln2_g, ln2_b, hbuf);
    gemm_rt<2, 512><<<4096, 256, 0, stream>>>(hbuf, wt_fc1, fc1_b, nullptr, big, nullptr, 32768, 2048, 16);
    gemm_rt<1, 2048><<<1024, 256, 0, stream>>>(big, wt_fc2, fc2_b, out, nullptr, out, 32768, 512, 4);
}